// Round 9
// baseline (101.604 us; speedup 1.0000x reference)
//
#include <hip/hip_runtime.h>
#include <hip/hip_bf16.h>

#define NN 50000
#define NE 800000
#define DIM 128
#define NBLK 49      // ceil(NN/1024) for fallback scan

// tier-0 partition geometry
#define NBUCK 196    // buckets of 256 nodes: bkt = dst>>8 (49999>>8 = 195)
#define CAP   6144   // edge capacity per bucket region (mean 4082, +32 sigma)
#define EPB   3200   // edges per partition block (250 blocks * 3200 = 800000)
#define PBLK  250
#define LCAP  1536   // per-slice LDS CSR capacity (mean 1024, +16 sigma)

typedef __attribute__((ext_vector_type(8))) short bf16x8;
typedef __attribute__((ext_vector_type(4))) float f32x4;

__device__ __forceinline__ short f2bf(float f) {
    union { float f; unsigned u; } x; x.f = f;
    unsigned r = x.u + 0x7fffu + ((x.u >> 16) & 1u);   // RNE
    return (short)(r >> 16);
}

__device__ __forceinline__ bf16x8 pack8(float4 a, float4 b) {
    bf16x8 v;
    v[0] = f2bf(a.x); v[1] = f2bf(a.y); v[2] = f2bf(a.z); v[3] = f2bf(a.w);
    v[4] = f2bf(b.x); v[5] = f2bf(b.y); v[6] = f2bf(b.z); v[7] = f2bf(b.w);
    return v;
}

__device__ __forceinline__ float bf2f(short s) {
    union { unsigned u; float f; } x; x.u = ((unsigned)(unsigned short)s) << 16;
    return x.f;
}

// Single accumulate body (round-7 lesson: one definition, no hand-unrolled copies).
__device__ __forceinline__ void acc8(f32x4& aA, f32x4& aB, bf16x8 x) {
    aA[0] += bf2f(x[0]); aA[1] += bf2f(x[1]); aA[2] += bf2f(x[2]); aA[3] += bf2f(x[3]);
    aB[0] += bf2f(x[4]); aB[1] += bf2f(x[5]); aB[2] += bf2f(x[6]); aB[3] += bf2f(x[7]);
}

// Graph-safe bucketFill reset.
__global__ __launch_bounds__(256) void zero_k(int* __restrict__ p) {
    p[threadIdx.x] = 0;
}

// ========================= tier-0: partition path ==========================

// blocks [0,3125): convert X -> bf16 shadow Xb.
// blocks [3125,3375): partition 3200 edges each via LDS counting sort.
// blocks 3375,3376: convert Ws/Wn -> swizzled bf16 image Wb (for cheap staging).
__global__ __launch_bounds__(256) void part1(const float* __restrict__ X,
                                             const int* __restrict__ src,
                                             const int* __restrict__ dst,
                                             const float* __restrict__ Ws,
                                             const float* __restrict__ Wn,
                                             short* __restrict__ Xb,
                                             short* __restrict__ Wb,
                                             int* __restrict__ bucketFill,
                                             unsigned* __restrict__ edges) {
    __shared__ unsigned stage[EPB];
    __shared__ unsigned sorted_[EPB];
    __shared__ int lcnt[256];
    __shared__ int lst[256];
    __shared__ int goff[256];
    __shared__ int c2[256];

    int b = blockIdx.x;
    int t = threadIdx.x;

    if (b < 3125) {             // X convert
        int i = b * 256 + t;    // exactly 800000 items of 8 floats
        const float4* p = (const float4*)(X + (size_t)i * 8);
        *(bf16x8*)(Xb + (size_t)i * 8) = pack8(p[0], p[1]);
        return;
    }
    if (b >= 3375) {            // W convert (swizzled image, same sc as wlds)
        int w = b - 3375;       // 0: Ws, 1: Wn
        const float* Wsrc = (w == 0) ? Ws : Wn;
        for (int i = t; i < 2048; i += 256) {
            int row = i >> 4;
            int c8 = (i & 15) << 3;
            int sc = c8 ^ ((row & 15) << 3);
            const float4* p = (const float4*)(Wsrc + row * DIM + c8);
            *(bf16x8*)(Wb + (size_t)w * 16384 + row * 128 + sc) = pack8(p[0], p[1]);
        }
        return;
    }

    int pb = b - 3125;          // partition block 0..249
    int e0 = pb * EPB;
    lcnt[t] = 0; c2[t] = 0;
    __syncthreads();

    // load + count (int4)
    for (int i = t * 4; i < EPB; i += 1024) {
        int4 s4 = *(const int4*)(src + e0 + i);
        int4 d4 = *(const int4*)(dst + e0 + i);
        int ss[4] = {s4.x, s4.y, s4.z, s4.w};
        int dd[4] = {d4.x, d4.y, d4.z, d4.w};
        #pragma unroll
        for (int j = 0; j < 4; ++j) {
            unsigned bk = (unsigned)dd[j] >> 8;
            unsigned dl = (unsigned)dd[j] & 255u;
            stage[i + j] = (bk << 24) | (dl << 16) | (unsigned)ss[j];
            atomicAdd(&lcnt[bk], 1);
        }
    }
    __syncthreads();

    // inclusive scan of lcnt[0..255]
    int v = lcnt[t];
    for (int off = 1; off < 256; off <<= 1) {
        __syncthreads();
        int tmp = (t >= off) ? lcnt[t - off] : 0;
        __syncthreads();
        lcnt[t] += tmp;
    }
    __syncthreads();
    int excl = lcnt[t] - v;
    lst[t] = excl;
    if (t < NBUCK) {
        int gb = atomicAdd(&bucketFill[t], v);
        goff[t] = t * CAP + gb - excl;
    }
    __syncthreads();

    // counting sort into sorted_
    for (int i = t * 4; i < EPB; i += 1024) {
        uint4 p4 = *(const uint4*)&stage[i];
        unsigned pp[4] = {p4.x, p4.y, p4.z, p4.w};
        #pragma unroll
        for (int j = 0; j < 4; ++j) {
            int bj = pp[j] >> 24;
            int r = atomicAdd(&c2[bj], 1);
            sorted_[lst[bj] + r] = pp[j];
        }
    }
    __syncthreads();

    // stream out in coalesced per-bucket runs
    for (int i = t * 4; i < EPB; i += 1024) {
        uint4 p4 = *(const uint4*)&sorted_[i];
        unsigned pp[4] = {p4.x, p4.y, p4.z, p4.w};
        #pragma unroll
        for (int j = 0; j < 4; ++j) {
            int bj = pp[j] >> 24;
            edges[(size_t)goff[bj] + i + j] = pp[j];
        }
    }
}

// Fused pull+GEMM: one block per 64-node bucket-slice (784 blocks).
// Phases: build slice CSR in LDS -> gather into swizzled LDS agg tile ->
// stage Ws, GEMM self-term -> restage Wn, GEMM neigh-term -> bias+ReLU store.
// LDS ~52KB -> 3 blocks/CU; phase-offset blocks overlap MFMA with gather.
__global__ __launch_bounds__(256, 3) void pullgemm(
        const short* __restrict__ Xb,
        const short* __restrict__ Wb,       // [2][128][128] swizzled bf16
        const int* __restrict__ bucketFill,
        const unsigned* __restrict__ edges,
        const float* __restrict__ bias,
        float* __restrict__ out) {
    __shared__ __align__(16) short wlds[128][128];   // 32 KB (Ws, then Wn)
    __shared__ __align__(16) short agg[64][128];     // 16 KB, XOR-swizzled
    __shared__ unsigned short lcsr[LCAP];            // 3 KB
    __shared__ int cnt[64];
    __shared__ int cur[64];
    __shared__ int start[65];

    int t = threadIdx.x;
    int b  = blockIdx.x >> 2;               // bucket
    int sl = blockIdx.x & 3;                // 64-node slice
    int dlo = sl * 64;
    int m = bucketFill[b];
    const unsigned* ed = edges + (size_t)b * CAP;

    if (t < 64) { cnt[t] = 0; cur[t] = 0; }
    __syncthreads();

    // ---- count owned dlocs (uint4) ----
    for (int i = t * 4; i < m; i += 1024) {
        if (i + 4 <= m) {
            uint4 e4 = *(const uint4*)(ed + i);
            unsigned pp[4] = {e4.x, e4.y, e4.z, e4.w};
            #pragma unroll
            for (int j = 0; j < 4; ++j) {
                int o = ((pp[j] >> 16) & 255u) - dlo;
                if ((unsigned)o < 64u) atomicAdd(&cnt[o], 1);
            }
        } else {
            for (int k = i; k < m; ++k) {
                int o = ((ed[k] >> 16) & 255u) - dlo;
                if ((unsigned)o < 64u) atomicAdd(&cnt[o], 1);
            }
        }
    }
    __syncthreads();

    // ---- exclusive scan of 64 counts ----
    int v0 = (t < 64) ? cnt[t] : 0;
    for (int off = 1; off < 64; off <<= 1) {
        __syncthreads();
        int tmp = (t >= off && t < 64) ? cnt[t - off] : 0;
        __syncthreads();
        if (t < 64) cnt[t] += tmp;
    }
    __syncthreads();
    if (t < 64) start[t] = cnt[t] - v0;
    if (t == 63) start[64] = cnt[63];
    __syncthreads();

    // ---- fill slice CSR in LDS ----
    for (int i = t * 4; i < m; i += 1024) {
        if (i + 4 <= m) {
            uint4 e4 = *(const uint4*)(ed + i);
            unsigned pp[4] = {e4.x, e4.y, e4.z, e4.w};
            #pragma unroll
            for (int j = 0; j < 4; ++j) {
                int o = ((pp[j] >> 16) & 255u) - dlo;
                if ((unsigned)o < 64u) {
                    int r = atomicAdd(&cur[o], 1);
                    int idx = start[o] + r;
                    if (idx < LCAP) lcsr[idx] = (unsigned short)(pp[j] & 0xffffu);
                }
            }
        } else {
            for (int k = i; k < m; ++k) {
                unsigned p = ed[k];
                int o = ((p >> 16) & 255u) - dlo;
                if ((unsigned)o < 64u) {
                    int r = atomicAdd(&cur[o], 1);
                    int idx = start[o] + r;
                    if (idx < LCAP) lcsr[idx] = (unsigned short)(p & 0xffffu);
                }
            }
        }
    }
    __syncthreads();

    // ---- pull: 4 waves, 16 nodes each; gather Xb rows -> LDS agg (swizzled)
    int lane = t & 63, wv = t >> 6;
    int g = lane >> 4, fl = lane & 15;
    const short* xbase = Xb + fl * 8;
    for (int n = wv; n < 64; n += 4) {
        int beg = start[n], end = start[n + 1];
        if (beg > LCAP) beg = LCAP;
        if (end > LCAP) end = LCAP;
        f32x4 aA = {0.f, 0.f, 0.f, 0.f}, aB = {0.f, 0.f, 0.f, 0.f};
        int e = beg;
        for (; e + 16 <= end; e += 16) {          // 4 row-loads in flight
            int v0i = lcsr[e + g];
            int v1i = lcsr[e + 4 + g];
            int v2i = lcsr[e + 8 + g];
            int v3i = lcsr[e + 12 + g];
            bf16x8 x0 = *(const bf16x8*)(xbase + (size_t)v0i * DIM);
            bf16x8 x1 = *(const bf16x8*)(xbase + (size_t)v1i * DIM);
            bf16x8 x2 = *(const bf16x8*)(xbase + (size_t)v2i * DIM);
            bf16x8 x3 = *(const bf16x8*)(xbase + (size_t)v3i * DIM);
            acc8(aA, aB, x0); acc8(aA, aB, x1);
            acc8(aA, aB, x2); acc8(aA, aB, x3);
        }
        for (; e + 8 <= end; e += 8) {
            int v0i = lcsr[e + g];
            int v1i = lcsr[e + 4 + g];
            bf16x8 x0 = *(const bf16x8*)(xbase + (size_t)v0i * DIM);
            bf16x8 x1 = *(const bf16x8*)(xbase + (size_t)v1i * DIM);
            acc8(aA, aB, x0); acc8(aA, aB, x1);
        }
        for (; e < end; e += 4) {
            int idx = e + g;
            int vv = lcsr[idx < end ? idx : beg];
            bf16x8 x = *(const bf16x8*)(xbase + (size_t)vv * DIM);
            if (idx < end) acc8(aA, aB, x);
        }
        #pragma unroll
        for (int i = 0; i < 4; ++i) {
            aA[i] += __shfl_xor(aA[i], 16); aA[i] += __shfl_xor(aA[i], 32);
            aB[i] += __shfl_xor(aB[i], 16); aB[i] += __shfl_xor(aB[i], 32);
        }
        if (g == 0) {
            bf16x8 r;
            r[0] = f2bf(aA[0]); r[1] = f2bf(aA[1]); r[2] = f2bf(aA[2]); r[3] = f2bf(aA[3]);
            r[4] = f2bf(aB[0]); r[5] = f2bf(aB[1]); r[6] = f2bf(aB[2]); r[7] = f2bf(aB[3]);
            // swizzle: chunk fl of row n stored at chunk (fl ^ (n&15))
            *(bf16x8*)&agg[n][8 * (fl ^ (n & 15))] = r;
        }
    }
    __syncthreads();

    // ---- stage Ws (flat copy of preconverted swizzled image) ----
    for (int i = t; i < 2048; i += 256)
        *(bf16x8*)((short*)wlds + (size_t)i * 8) = *(const bf16x8*)(Wb + (size_t)i * 8);
    __syncthreads();

    // ---- GEMM self-term: acc += Xb_rows @ Ws^T ----
    int n0 = b * 256 + dlo + wv * 16;                 // wave's first global row
    int arow = n0 + (lane & 15);
    int rowc = arow < NN ? arow : (NN - 1);
    const short* xr = Xb + (size_t)rowc * DIM + (lane >> 4) * 8;

    f32x4 acc[8] = {};
    #pragma unroll
    for (int ks = 0; ks < 4; ++ks) {
        int k0 = ks * 32;
        bf16x8 afx = *(const bf16x8*)(xr + k0);
        int bcol = k0 + (lane >> 4) * 8;
        #pragma unroll
        for (int ot = 0; ot < 8; ++ot) {
            int brow = ot * 16 + (lane & 15);
            int sc = bcol ^ ((brow & 15) << 3);
            bf16x8 bs = *(const bf16x8*)&wlds[brow][sc];
            acc[ot] = __builtin_amdgcn_mfma_f32_16x16x32_bf16(afx, bs, acc[ot], 0, 0, 0);
        }
    }
    __syncthreads();

    // ---- restage Wn ----
    for (int i = t; i < 2048; i += 256)
        *(bf16x8*)((short*)wlds + (size_t)i * 8) = *(const bf16x8*)(Wb + 16384 + (size_t)i * 8);
    __syncthreads();

    // ---- GEMM neighbor-term: acc += agg_rows @ Wn^T (A from LDS, swizzled)
    int ra = lane & 15;                                // row within wave tile
    int cb = lane >> 4;                                // chunk group 0..3
    #pragma unroll
    for (int ks = 0; ks < 4; ++ks) {
        int c = ks * 4 + cb;                           // chunk 0..15
        bf16x8 afg = *(const bf16x8*)&agg[wv * 16 + ra][8 * (c ^ ra)];
        int bcol = ks * 32 + cb * 8;
        #pragma unroll
        for (int ot = 0; ot < 8; ++ot) {
            int brow = ot * 16 + ra;
            int sc = bcol ^ ((brow & 15) << 3);
            bf16x8 bn = *(const bf16x8*)&wlds[brow][sc];
            acc[ot] = __builtin_amdgcn_mfma_f32_16x16x32_bf16(afg, bn, acc[ot], 0, 0, 0);
        }
    }

    // ---- epilogue: bias + ReLU ----
    int col0 = lane & 15;
    int rbase = n0 + (lane >> 4) * 4;
    #pragma unroll
    for (int ot = 0; ot < 8; ++ot) {
        int col = ot * 16 + col0;
        float bv = bias[col];
        #pragma unroll
        for (int i = 0; i < 4; ++i) {
            int r = rbase + i;
            if (r < NN) out[(size_t)r * DIM + col] = fmaxf(acc[ot][i] + bv, 0.f);
        }
    }
}

// ===================== tier-2/3 fallback kernels ===========================

__global__ __launch_bounds__(256) void hist_k(const int* __restrict__ dst,
                                              int* __restrict__ cnt) {
    int e = blockIdx.x * 256 + threadIdx.x;
    if (e < NE) atomicAdd(&cnt[dst[e]], 1);
}

__global__ __launch_bounds__(1024) void scanA(const int* __restrict__ cnt,
                                              int* __restrict__ rowstart,
                                              int* __restrict__ bsum) {
    __shared__ int s[1024];
    int i = blockIdx.x * 1024 + threadIdx.x;
    int v = (i < NN) ? cnt[i] : 0;
    s[threadIdx.x] = v;
    for (int off = 1; off < 1024; off <<= 1) {
        __syncthreads();
        int t = (threadIdx.x >= off) ? s[threadIdx.x - off] : 0;
        __syncthreads();
        s[threadIdx.x] += t;
    }
    __syncthreads();
    if (i < NN) rowstart[i] = s[threadIdx.x] - v;
    if (threadIdx.x == 1023) bsum[blockIdx.x] = s[1023];
}

__global__ __launch_bounds__(64) void scanB(int* __restrict__ bsum) {
    int l = threadIdx.x;
    int orig = (l < NBLK) ? bsum[l] : 0;
    int v = orig;
    for (int off = 1; off < 64; off <<= 1) {
        int t = __shfl_up(v, off);
        if (l >= off) v += t;
    }
    if (l < NBLK) bsum[l] = v - orig;
}

__global__ __launch_bounds__(1024) void scanC(int* __restrict__ rowstart,
                                              const int* __restrict__ bsum) {
    int i = blockIdx.x * 1024 + threadIdx.x;
    if (i < NN) rowstart[i] += bsum[blockIdx.x];
    if (i == 0) rowstart[NN] = NE;
}

__global__ __launch_bounds__(256) void fill_atomic(const int* __restrict__ src,
                                                   const int* __restrict__ dst,
                                                   int* __restrict__ rowstart,
                                                   int* __restrict__ csr) {
    int e = blockIdx.x * 256 + threadIdx.x;
    if (e < NE) {
        int p = atomicAdd(&rowstart[dst[e]], 1);
        csr[p] = src[e];
    }
}

__global__ __launch_bounds__(256) void cvt_k(const float* __restrict__ X,
                                             short* __restrict__ Xb) {
    int i = blockIdx.x * 256 + threadIdx.x;
    if (i < NN * DIM / 8) {
        const float4* p = (const float4*)(X + (size_t)i * 8);
        *(bf16x8*)(Xb + (size_t)i * 8) = pack8(p[0], p[1]);
    }
}

__global__ __launch_bounds__(256) void pull_bf16(const short* __restrict__ Xb,
                                                 const int* __restrict__ rowend,
                                                 const int* __restrict__ csr,
                                                 float* __restrict__ agg) {
    int lane = threadIdx.x & 63;
    int u = (blockIdx.x * 256 + threadIdx.x) >> 6;
    if (u >= NN) return;
    int beg = (u == 0) ? 0 : rowend[u - 1];
    int end = rowend[u];
    float2 a0 = {0.f, 0.f}, a1 = {0.f, 0.f};
    int e = beg;
    for (; e + 1 < end; e += 2) {
        int v0 = csr[e], v1 = csr[e + 1];
        ushort2 x0 = *(const ushort2*)(Xb + (size_t)v0 * DIM + lane * 2);
        ushort2 x1 = *(const ushort2*)(Xb + (size_t)v1 * DIM + lane * 2);
        a0.x += bf2f(x0.x); a0.y += bf2f(x0.y);
        a1.x += bf2f(x1.x); a1.y += bf2f(x1.y);
    }
    if (e < end) {
        int v0 = csr[e];
        ushort2 x0 = *(const ushort2*)(Xb + (size_t)v0 * DIM + lane * 2);
        a0.x += bf2f(x0.x); a0.y += bf2f(x0.y);
    }
    float2 r = {a0.x + a1.x, a0.y + a1.y};
    *(float2*)(agg + (size_t)u * DIM + lane * 2) = r;
}

__global__ __launch_bounds__(256) void scatter_k(const float* __restrict__ X,
                                                 const int* __restrict__ src,
                                                 const int* __restrict__ dst,
                                                 float* __restrict__ agg) {
    int lane = threadIdx.x & 63;
    int gw = (blockIdx.x * 256 + threadIdx.x) >> 6;
    int nw = (gridDim.x * 256) >> 6;
    for (int e = gw; e < NE; e += nw) {
        int s = src[e];
        int d = dst[e];
        float2 v = *(const float2*)(X + (size_t)s * DIM + lane * 2);
        float* a = agg + (size_t)d * DIM + lane * 2;
        unsafeAtomicAdd(a, v.x);
        unsafeAtomicAdd(a + 1, v.y);
    }
}

__global__ __launch_bounds__(256) void fused_gemm(
        const float* __restrict__ X,
        const float* __restrict__ agg,
        const float* __restrict__ Ws,
        const float* __restrict__ Wn,
        const float* __restrict__ bias,
        float* __restrict__ out) {
    __shared__ __align__(16) short wlds[2][128][128];
    for (int i = threadIdx.x; i < 128 * 16; i += 256) {
        int row = i >> 4;
        int c8 = (i & 15) << 3;
        int sc = c8 ^ ((row & 15) << 3);
        const float4* ps = (const float4*)(Ws + row * DIM + c8);
        *(bf16x8*)&wlds[0][row][sc] = pack8(ps[0], ps[1]);
        const float4* pn = (const float4*)(Wn + row * DIM + c8);
        *(bf16x8*)&wlds[1][row][sc] = pack8(pn[0], pn[1]);
    }
    __syncthreads();

    int lane = threadIdx.x & 63;
    int wv = threadIdx.x >> 6;
    int n0 = blockIdx.x * 64 + wv * 16;
    int arow = n0 + (lane & 15);
    int rowc = arow < NN ? arow : (NN - 1);
    const float* xr = X + (size_t)rowc * DIM + (lane >> 4) * 8;
    const float* ar = agg + (size_t)rowc * DIM + (lane >> 4) * 8;

    f32x4 acc[8] = {};
    #pragma unroll
    for (int ks = 0; ks < 4; ++ks) {
        int k0 = ks * 32;
        float4 xa = *(const float4*)(xr + k0);
        float4 xb = *(const float4*)(xr + k0 + 4);
        bf16x8 afx = pack8(xa, xb);
        float4 ga = *(const float4*)(ar + k0);
        float4 gb = *(const float4*)(ar + k0 + 4);
        bf16x8 afg = pack8(ga, gb);
        int bcol = k0 + (lane >> 4) * 8;
        #pragma unroll
        for (int ot = 0; ot < 8; ++ot) {
            int brow = ot * 16 + (lane & 15);
            int sc = bcol ^ ((brow & 15) << 3);
            bf16x8 bs = *(const bf16x8*)&wlds[0][brow][sc];
            bf16x8 bn = *(const bf16x8*)&wlds[1][brow][sc];
            acc[ot] = __builtin_amdgcn_mfma_f32_16x16x32_bf16(afx, bs, acc[ot], 0, 0, 0);
            acc[ot] = __builtin_amdgcn_mfma_f32_16x16x32_bf16(afg, bn, acc[ot], 0, 0, 0);
        }
    }

    int col0 = lane & 15;
    int rbase = n0 + (lane >> 4) * 4;
    #pragma unroll
    for (int ot = 0; ot < 8; ++ot) {
        int col = ot * 16 + col0;
        float bv = bias[col];
        #pragma unroll
        for (int i = 0; i < 4; ++i) {
            int r = rbase + i;
            if (r < NN) out[(size_t)r * DIM + col] = fmaxf(acc[ot][i] + bv, 0.f);
        }
    }
}

// ===========================================================================

extern "C" void kernel_launch(void* const* d_in, const int* in_sizes, int n_in,
                              void* d_out, int out_size, void* d_ws, size_t ws_size,
                              hipStream_t stream) {
    const float* X    = (const float*)d_in[0];
    const int*   src  = (const int*)  d_in[1];
    const int*   dst  = (const int*)  d_in[2];
    const float* Ws   = (const float*)d_in[3];
    const float* Wn   = (const float*)d_in[4];
    const float* bias = (const float*)d_in[5];
    float* out = (float*)d_out;

    // tier-0 ws layout: bucketFill[256] ints | edges[196*6144] u32 |
    //   Xb (NN*DIM shorts) | Wb (2*128*128 shorts)   ~= 17.7 MB
    const size_t REQ0 = (size_t)256 * 4 + (size_t)NBUCK * CAP * 4
                      + (size_t)NN * DIM * 2 + (size_t)32768 * 2;
    // tier-2 (round-2 style): ~16.4 MB
    const size_t REQ2 = (size_t)(50048 + 50056 + 64 + 800000) * 4
                      + (size_t)NN * DIM * 2;

    if (ws_size >= REQ0) {
        int*      bf    = (int*)d_ws;
        unsigned* edges = (unsigned*)(bf + 256);
        short*    Xb    = (short*)(edges + (size_t)NBUCK * CAP);
        short*    Wb    = Xb + (size_t)NN * DIM;

        zero_k<<<1, 256, 0, stream>>>(bf);
        part1<<<3125 + PBLK + 2, 256, 0, stream>>>(X, src, dst, Ws, Wn, Xb, Wb, bf, edges);
        pullgemm<<<NBUCK * 4, 256, 0, stream>>>(Xb, Wb, bf, edges, bias, out);
    } else if (ws_size >= REQ2) {
        int* cnt      = (int*)d_ws;
        int* rowstart = cnt + 50048;
        int* bsum     = rowstart + 50056;
        int* csr      = bsum + 64;
        short* Xb     = (short*)(csr + 800000);

        hipMemsetAsync(cnt, 0, 50048 * sizeof(int), stream);
        hist_k<<<3125, 256, 0, stream>>>(dst, cnt);
        scanA<<<NBLK, 1024, 0, stream>>>(cnt, rowstart, bsum);
        scanB<<<1, 64, 0, stream>>>(bsum);
        scanC<<<NBLK, 1024, 0, stream>>>(rowstart, bsum);
        fill_atomic<<<3125, 256, 0, stream>>>(src, dst, rowstart, csr);
        cvt_k<<<3125, 256, 0, stream>>>(X, Xb);
        pull_bf16<<<12500, 256, 0, stream>>>(Xb, rowstart, csr, out);
        fused_gemm<<<(NN + 63) / 64, 256, 0, stream>>>(X, out, Ws, Wn, bias, out);
    } else {
        hipMemsetAsync(out, 0, (size_t)NN * DIM * sizeof(float), stream);
        scatter_k<<<2048, 256, 0, stream>>>(X, src, dst, out);
        fused_gemm<<<(NN + 63) / 64, 256, 0, stream>>>(X, out, Ws, Wn, bias, out);
    }
}

// Round 10
// 74.412 us; speedup vs baseline: 1.3654x; 1.3654x over previous
//
#include <hip/hip_runtime.h>
#include <hip/hip_bf16.h>

#define NN 50000
#define NE 800000
#define DIM 128
#define NBLK 49      // ceil(NN/1024) for fallback scan

// tier-0 partition geometry
#define NBUCK 196    // buckets of 256 nodes: bkt = dst>>8 (49999>>8 = 195)
#define CAP   6144   // edge capacity per bucket region (mean 4082, +32 sigma)
#define EPB   3200   // edges per partition block (250 blocks * 3200 = 800000)
#define PBLK  250
#define LCAP  2048   // per-64-node-slice LDS CSR capacity (mean 1024, +32 sigma)

typedef __attribute__((ext_vector_type(8))) short bf16x8;
typedef __attribute__((ext_vector_type(4))) float f32x4;

__device__ __forceinline__ short f2bf(float f) {
    union { float f; unsigned u; } x; x.f = f;
    unsigned r = x.u + 0x7fffu + ((x.u >> 16) & 1u);   // RNE
    return (short)(r >> 16);
}

__device__ __forceinline__ bf16x8 pack8(float4 a, float4 b) {
    bf16x8 v;
    v[0] = f2bf(a.x); v[1] = f2bf(a.y); v[2] = f2bf(a.z); v[3] = f2bf(a.w);
    v[4] = f2bf(b.x); v[5] = f2bf(b.y); v[6] = f2bf(b.z); v[7] = f2bf(b.w);
    return v;
}

__device__ __forceinline__ float bf2f(short s) {
    union { unsigned u; float f; } x; x.u = ((unsigned)(unsigned short)s) << 16;
    return x.f;
}

// Single accumulate body (round-7 lesson: one definition only).
__device__ __forceinline__ void acc8(f32x4& aA, f32x4& aB, bf16x8 x) {
    aA[0] += bf2f(x[0]); aA[1] += bf2f(x[1]); aA[2] += bf2f(x[2]); aA[3] += bf2f(x[3]);
    aB[0] += bf2f(x[4]); aB[1] += bf2f(x[5]); aB[2] += bf2f(x[6]); aB[3] += bf2f(x[7]);
}

// Graph-safe bucketFill reset.
__global__ __launch_bounds__(256) void zero_k(int* __restrict__ p) {
    p[threadIdx.x] = 0;
}

// ========================= tier-0: partition path ==========================

// blocks [0,3125): convert X -> bf16 shadow Xb.
// blocks [3125,3375): partition 3200 edges each via LDS counting sort.
// blocks 3375,3376: convert Ws/Wn -> swizzled bf16 image Wb.
__global__ __launch_bounds__(256) void part1(const float* __restrict__ X,
                                             const int* __restrict__ src,
                                             const int* __restrict__ dst,
                                             const float* __restrict__ Ws,
                                             const float* __restrict__ Wn,
                                             short* __restrict__ Xb,
                                             short* __restrict__ Wb,
                                             int* __restrict__ bucketFill,
                                             unsigned* __restrict__ edges) {
    __shared__ unsigned stage[EPB];
    __shared__ unsigned sorted_[EPB];
    __shared__ int lcnt[256];
    __shared__ int lst[256];
    __shared__ int goff[256];
    __shared__ int c2[256];

    int b = blockIdx.x;
    int t = threadIdx.x;

    if (b < 3125) {             // X convert
        int i = b * 256 + t;    // exactly 800000 items of 8 floats
        const float4* p = (const float4*)(X + (size_t)i * 8);
        *(bf16x8*)(Xb + (size_t)i * 8) = pack8(p[0], p[1]);
        return;
    }
    if (b >= 3375) {            // W convert (swizzled image, same sc as wlds)
        int w = b - 3375;       // 0: Ws, 1: Wn
        const float* Wsrc = (w == 0) ? Ws : Wn;
        for (int i = t; i < 2048; i += 256) {
            int row = i >> 4;
            int c8 = (i & 15) << 3;
            int sc = c8 ^ ((row & 15) << 3);
            const float4* p = (const float4*)(Wsrc + row * DIM + c8);
            *(bf16x8*)(Wb + (size_t)w * 16384 + row * 128 + sc) = pack8(p[0], p[1]);
        }
        return;
    }

    int pb = b - 3125;          // partition block 0..249
    int e0 = pb * EPB;
    lcnt[t] = 0; c2[t] = 0;
    __syncthreads();

    // load + count (int4)
    for (int i = t * 4; i < EPB; i += 1024) {
        int4 s4 = *(const int4*)(src + e0 + i);
        int4 d4 = *(const int4*)(dst + e0 + i);
        int ss[4] = {s4.x, s4.y, s4.z, s4.w};
        int dd[4] = {d4.x, d4.y, d4.z, d4.w};
        #pragma unroll
        for (int j = 0; j < 4; ++j) {
            unsigned bk = (unsigned)dd[j] >> 8;
            unsigned dl = (unsigned)dd[j] & 255u;
            stage[i + j] = (bk << 24) | (dl << 16) | (unsigned)ss[j];
            atomicAdd(&lcnt[bk], 1);
        }
    }
    __syncthreads();

    // inclusive scan of lcnt[0..255]
    int v = lcnt[t];
    for (int off = 1; off < 256; off <<= 1) {
        __syncthreads();
        int tmp = (t >= off) ? lcnt[t - off] : 0;
        __syncthreads();
        lcnt[t] += tmp;
    }
    __syncthreads();
    int excl = lcnt[t] - v;
    lst[t] = excl;
    if (t < NBUCK) {
        int gb = atomicAdd(&bucketFill[t], v);
        goff[t] = t * CAP + gb - excl;
    }
    __syncthreads();

    // counting sort into sorted_
    for (int i = t * 4; i < EPB; i += 1024) {
        uint4 p4 = *(const uint4*)&stage[i];
        unsigned pp[4] = {p4.x, p4.y, p4.z, p4.w};
        #pragma unroll
        for (int j = 0; j < 4; ++j) {
            int bj = pp[j] >> 24;
            int r = atomicAdd(&c2[bj], 1);
            sorted_[lst[bj] + r] = pp[j];
        }
    }
    __syncthreads();

    // stream out in coalesced per-bucket runs
    for (int i = t * 4; i < EPB; i += 1024) {
        uint4 p4 = *(const uint4*)&sorted_[i];
        unsigned pp[4] = {p4.x, p4.y, p4.z, p4.w};
        #pragma unroll
        for (int j = 0; j < 4; ++j) {
            int bj = pp[j] >> 24;
            edges[(size_t)goff[bj] + i + j] = pp[j];
        }
    }
}

// One block per (bucket, 64-node slice): 784 blocks x 512 thr. Slice CSR in
// LDS (4 scans of each bucket's edges grid-wide vs round-8's 8), then
// wave-per-node gather of Xb rows into bf16 aggb. Small LDS -> max occupancy.
__global__ __launch_bounds__(512) void pull2(const short* __restrict__ Xb,
                                             const int* __restrict__ bucketFill,
                                             const unsigned* __restrict__ edges,
                                             short* __restrict__ aggb) {
    __shared__ int cnt[64];
    __shared__ int c2s[64];
    __shared__ int start[65];
    __shared__ unsigned short lcsr[LCAP];

    int t = threadIdx.x;
    int b  = blockIdx.x >> 2;               // bucket
    int sl = blockIdx.x & 3;                // 64-node slice
    int dlo = sl * 64;
    int m = bucketFill[b];
    const unsigned* ed = edges + (size_t)b * CAP;

    if (t < 64) { cnt[t] = 0; c2s[t] = 0; }
    __syncthreads();

    // count owned dlocs (uint4)
    for (int i = t * 4; i < m; i += 2048) {
        if (i + 4 <= m) {
            uint4 e4 = *(const uint4*)(ed + i);
            unsigned pp[4] = {e4.x, e4.y, e4.z, e4.w};
            #pragma unroll
            for (int j = 0; j < 4; ++j) {
                int o = ((pp[j] >> 16) & 255u) - dlo;
                if ((unsigned)o < 64u) atomicAdd(&cnt[o], 1);
            }
        } else {
            for (int k = i; k < m; ++k) {
                int o = ((ed[k] >> 16) & 255u) - dlo;
                if ((unsigned)o < 64u) atomicAdd(&cnt[o], 1);
            }
        }
    }
    __syncthreads();

    // exclusive scan of 64 counts
    int v = (t < 64) ? cnt[t] : 0;
    for (int off = 1; off < 64; off <<= 1) {
        __syncthreads();
        int tmp = (t >= off && t < 64) ? cnt[t - off] : 0;
        __syncthreads();
        if (t < 64) cnt[t] += tmp;
    }
    __syncthreads();
    if (t < 64) start[t] = cnt[t] - v;
    if (t == 63) start[64] = cnt[63];
    __syncthreads();

    // fill slice CSR (uint4)
    for (int i = t * 4; i < m; i += 2048) {
        if (i + 4 <= m) {
            uint4 e4 = *(const uint4*)(ed + i);
            unsigned pp[4] = {e4.x, e4.y, e4.z, e4.w};
            #pragma unroll
            for (int j = 0; j < 4; ++j) {
                int o = ((pp[j] >> 16) & 255u) - dlo;
                if ((unsigned)o < 64u) {
                    int r = atomicAdd(&c2s[o], 1);
                    int idx = start[o] + r;
                    if (idx < LCAP) lcsr[idx] = (unsigned short)(pp[j] & 0xffffu);
                }
            }
        } else {
            for (int k = i; k < m; ++k) {
                unsigned p = ed[k];
                int o = ((p >> 16) & 255u) - dlo;
                if ((unsigned)o < 64u) {
                    int r = atomicAdd(&c2s[o], 1);
                    int idx = start[o] + r;
                    if (idx < LCAP) lcsr[idx] = (unsigned short)(p & 0xffffu);
                }
            }
        }
    }
    __syncthreads();

    // pull: 8 waves, 8 nodes each; 16 lanes x 16B per row, 4 row-slots/load
    int lane = t & 63, wv = t >> 6;
    int g = lane >> 4, fl = lane & 15;
    const short* xbase = Xb + fl * 8;
    for (int n = wv; n < 64; n += 8) {
        int u = (b << 8) + dlo + n;
        if (u >= NN) continue;
        int beg = start[n], end = start[n + 1];
        if (beg > LCAP) beg = LCAP;
        if (end > LCAP) end = LCAP;
        f32x4 aA = {0.f, 0.f, 0.f, 0.f}, aB = {0.f, 0.f, 0.f, 0.f};
        int e = beg;
        for (; e + 16 <= end; e += 16) {          // 4 row-loads in flight
            int v0 = lcsr[e + g];
            int v1 = lcsr[e + 4 + g];
            int v2 = lcsr[e + 8 + g];
            int v3 = lcsr[e + 12 + g];
            bf16x8 x0 = *(const bf16x8*)(xbase + (size_t)v0 * DIM);
            bf16x8 x1 = *(const bf16x8*)(xbase + (size_t)v1 * DIM);
            bf16x8 x2 = *(const bf16x8*)(xbase + (size_t)v2 * DIM);
            bf16x8 x3 = *(const bf16x8*)(xbase + (size_t)v3 * DIM);
            acc8(aA, aB, x0); acc8(aA, aB, x1);
            acc8(aA, aB, x2); acc8(aA, aB, x3);
        }
        for (; e + 8 <= end; e += 8) {
            int v0 = lcsr[e + g];
            int v1 = lcsr[e + 4 + g];
            bf16x8 x0 = *(const bf16x8*)(xbase + (size_t)v0 * DIM);
            bf16x8 x1 = *(const bf16x8*)(xbase + (size_t)v1 * DIM);
            acc8(aA, aB, x0); acc8(aA, aB, x1);
        }
        for (; e < end; e += 4) {
            int idx = e + g;
            int vv = lcsr[idx < end ? idx : beg];
            bf16x8 x = *(const bf16x8*)(xbase + (size_t)vv * DIM);
            if (idx < end) acc8(aA, aB, x);
        }
        #pragma unroll
        for (int i = 0; i < 4; ++i) {
            aA[i] += __shfl_xor(aA[i], 16); aA[i] += __shfl_xor(aA[i], 32);
            aB[i] += __shfl_xor(aB[i], 16); aB[i] += __shfl_xor(aB[i], 32);
        }
        if (g == 0) {
            bf16x8 r;
            r[0] = f2bf(aA[0]); r[1] = f2bf(aA[1]); r[2] = f2bf(aA[2]); r[3] = f2bf(aA[3]);
            r[4] = f2bf(aB[0]); r[5] = f2bf(aB[1]); r[6] = f2bf(aB[2]); r[7] = f2bf(aB[3]);
            *(bf16x8*)(aggb + (size_t)u * DIM + fl * 8) = r;
        }
    }
}

// out = ReLU(Xb@Ws^T + aggb@Wn^T + bias). 128-row blocks, 8 waves (512 thr);
// W staged by flat copy of the preconverted swizzled Wb image (no pack VALU).
__global__ __launch_bounds__(512) void gemm_bb(const short* __restrict__ Xb,
                                               const short* __restrict__ aggb,
                                               const short* __restrict__ Wb,
                                               const float* __restrict__ bias,
                                               float* __restrict__ out) {
    __shared__ __align__(16) short wlds[2][128][128];
    for (int i = threadIdx.x; i < 4096; i += 512)
        *(bf16x8*)((short*)wlds + (size_t)i * 8) = *(const bf16x8*)(Wb + (size_t)i * 8);
    __syncthreads();

    int lane = threadIdx.x & 63;
    int wv = threadIdx.x >> 6;                 // 0..7
    int n0 = blockIdx.x * 128 + wv * 16;
    int arow = n0 + (lane & 15);
    int rowc = arow < NN ? arow : (NN - 1);
    const short* xr = Xb   + (size_t)rowc * DIM + (lane >> 4) * 8;
    const short* ar = aggb + (size_t)rowc * DIM + (lane >> 4) * 8;

    f32x4 acc[8] = {};
    #pragma unroll
    for (int ks = 0; ks < 4; ++ks) {
        int k0 = ks * 32;
        bf16x8 afx = *(const bf16x8*)(xr + k0);
        bf16x8 afg = *(const bf16x8*)(ar + k0);
        int bcol = k0 + (lane >> 4) * 8;
        #pragma unroll
        for (int ot = 0; ot < 8; ++ot) {
            int brow = ot * 16 + (lane & 15);
            int sc = bcol ^ ((brow & 15) << 3);
            bf16x8 bs = *(const bf16x8*)&wlds[0][brow][sc];
            bf16x8 bn = *(const bf16x8*)&wlds[1][brow][sc];
            acc[ot] = __builtin_amdgcn_mfma_f32_16x16x32_bf16(afx, bs, acc[ot], 0, 0, 0);
            acc[ot] = __builtin_amdgcn_mfma_f32_16x16x32_bf16(afg, bn, acc[ot], 0, 0, 0);
        }
    }

    int col0 = lane & 15;
    int rbase = n0 + (lane >> 4) * 4;
    #pragma unroll
    for (int ot = 0; ot < 8; ++ot) {
        int col = ot * 16 + col0;
        float bv = bias[col];
        #pragma unroll
        for (int i = 0; i < 4; ++i) {
            int r = rbase + i;
            if (r < NN) out[(size_t)r * DIM + col] = fmaxf(acc[ot][i] + bv, 0.f);
        }
    }
}

// ===================== tier-2/3 fallback kernels ===========================

__global__ __launch_bounds__(256) void hist_k(const int* __restrict__ dst,
                                              int* __restrict__ cnt) {
    int e = blockIdx.x * 256 + threadIdx.x;
    if (e < NE) atomicAdd(&cnt[dst[e]], 1);
}

__global__ __launch_bounds__(1024) void scanA(const int* __restrict__ cnt,
                                              int* __restrict__ rowstart,
                                              int* __restrict__ bsum) {
    __shared__ int s[1024];
    int i = blockIdx.x * 1024 + threadIdx.x;
    int v = (i < NN) ? cnt[i] : 0;
    s[threadIdx.x] = v;
    for (int off = 1; off < 1024; off <<= 1) {
        __syncthreads();
        int t = (threadIdx.x >= off) ? s[threadIdx.x - off] : 0;
        __syncthreads();
        s[threadIdx.x] += t;
    }
    __syncthreads();
    if (i < NN) rowstart[i] = s[threadIdx.x] - v;
    if (threadIdx.x == 1023) bsum[blockIdx.x] = s[1023];
}

__global__ __launch_bounds__(64) void scanB(int* __restrict__ bsum) {
    int l = threadIdx.x;
    int orig = (l < NBLK) ? bsum[l] : 0;
    int v = orig;
    for (int off = 1; off < 64; off <<= 1) {
        int t = __shfl_up(v, off);
        if (l >= off) v += t;
    }
    if (l < NBLK) bsum[l] = v - orig;
}

__global__ __launch_bounds__(1024) void scanC(int* __restrict__ rowstart,
                                              const int* __restrict__ bsum) {
    int i = blockIdx.x * 1024 + threadIdx.x;
    if (i < NN) rowstart[i] += bsum[blockIdx.x];
    if (i == 0) rowstart[NN] = NE;
}

__global__ __launch_bounds__(256) void fill_atomic(const int* __restrict__ src,
                                                   const int* __restrict__ dst,
                                                   int* __restrict__ rowstart,
                                                   int* __restrict__ csr) {
    int e = blockIdx.x * 256 + threadIdx.x;
    if (e < NE) {
        int p = atomicAdd(&rowstart[dst[e]], 1);
        csr[p] = src[e];
    }
}

__global__ __launch_bounds__(256) void cvt_k(const float* __restrict__ X,
                                             short* __restrict__ Xb) {
    int i = blockIdx.x * 256 + threadIdx.x;
    if (i < NN * DIM / 8) {
        const float4* p = (const float4*)(X + (size_t)i * 8);
        *(bf16x8*)(Xb + (size_t)i * 8) = pack8(p[0], p[1]);
    }
}

__global__ __launch_bounds__(256) void pull_bf16(const short* __restrict__ Xb,
                                                 const int* __restrict__ rowend,
                                                 const int* __restrict__ csr,
                                                 float* __restrict__ agg) {
    int lane = threadIdx.x & 63;
    int u = (blockIdx.x * 256 + threadIdx.x) >> 6;
    if (u >= NN) return;
    int beg = (u == 0) ? 0 : rowend[u - 1];
    int end = rowend[u];
    float2 a0 = {0.f, 0.f}, a1 = {0.f, 0.f};
    int e = beg;
    for (; e + 1 < end; e += 2) {
        int v0 = csr[e], v1 = csr[e + 1];
        ushort2 x0 = *(const ushort2*)(Xb + (size_t)v0 * DIM + lane * 2);
        ushort2 x1 = *(const ushort2*)(Xb + (size_t)v1 * DIM + lane * 2);
        a0.x += bf2f(x0.x); a0.y += bf2f(x0.y);
        a1.x += bf2f(x1.x); a1.y += bf2f(x1.y);
    }
    if (e < end) {
        int v0 = csr[e];
        ushort2 x0 = *(const ushort2*)(Xb + (size_t)v0 * DIM + lane * 2);
        a0.x += bf2f(x0.x); a0.y += bf2f(x0.y);
    }
    float2 r = {a0.x + a1.x, a0.y + a1.y};
    *(float2*)(agg + (size_t)u * DIM + lane * 2) = r;
}

__global__ __launch_bounds__(256) void scatter_k(const float* __restrict__ X,
                                                 const int* __restrict__ src,
                                                 const int* __restrict__ dst,
                                                 float* __restrict__ agg) {
    int lane = threadIdx.x & 63;
    int gw = (blockIdx.x * 256 + threadIdx.x) >> 6;
    int nw = (gridDim.x * 256) >> 6;
    for (int e = gw; e < NE; e += nw) {
        int s = src[e];
        int d = dst[e];
        float2 v = *(const float2*)(X + (size_t)s * DIM + lane * 2);
        float* a = agg + (size_t)d * DIM + lane * 2;
        unsafeAtomicAdd(a, v.x);
        unsafeAtomicAdd(a + 1, v.y);
    }
}

__global__ __launch_bounds__(256) void fused_gemm(
        const float* __restrict__ X,
        const float* __restrict__ agg,
        const float* __restrict__ Ws,
        const float* __restrict__ Wn,
        const float* __restrict__ bias,
        float* __restrict__ out) {
    __shared__ __align__(16) short wlds[2][128][128];
    for (int i = threadIdx.x; i < 128 * 16; i += 256) {
        int row = i >> 4;
        int c8 = (i & 15) << 3;
        int sc = c8 ^ ((row & 15) << 3);
        const float4* ps = (const float4*)(Ws + row * DIM + c8);
        *(bf16x8*)&wlds[0][row][sc] = pack8(ps[0], ps[1]);
        const float4* pn = (const float4*)(Wn + row * DIM + c8);
        *(bf16x8*)&wlds[1][row][sc] = pack8(pn[0], pn[1]);
    }
    __syncthreads();

    int lane = threadIdx.x & 63;
    int wv = threadIdx.x >> 6;
    int n0 = blockIdx.x * 64 + wv * 16;
    int arow = n0 + (lane & 15);
    int rowc = arow < NN ? arow : (NN - 1);
    const float* xr = X + (size_t)rowc * DIM + (lane >> 4) * 8;
    const float* ar = agg + (size_t)rowc * DIM + (lane >> 4) * 8;

    f32x4 acc[8] = {};
    #pragma unroll
    for (int ks = 0; ks < 4; ++ks) {
        int k0 = ks * 32;
        float4 xa = *(const float4*)(xr + k0);
        float4 xb = *(const float4*)(xr + k0 + 4);
        bf16x8 afx = pack8(xa, xb);
        float4 ga = *(const float4*)(ar + k0);
        float4 gb = *(const float4*)(ar + k0 + 4);
        bf16x8 afg = pack8(ga, gb);
        int bcol = k0 + (lane >> 4) * 8;
        #pragma unroll
        for (int ot = 0; ot < 8; ++ot) {
            int brow = ot * 16 + (lane & 15);
            int sc = bcol ^ ((brow & 15) << 3);
            bf16x8 bs = *(const bf16x8*)&wlds[0][brow][sc];
            bf16x8 bn = *(const bf16x8*)&wlds[1][brow][sc];
            acc[ot] = __builtin_amdgcn_mfma_f32_16x16x32_bf16(afx, bs, acc[ot], 0, 0, 0);
            acc[ot] = __builtin_amdgcn_mfma_f32_16x16x32_bf16(afg, bn, acc[ot], 0, 0, 0);
        }
    }

    int col0 = lane & 15;
    int rbase = n0 + (lane >> 4) * 4;
    #pragma unroll
    for (int ot = 0; ot < 8; ++ot) {
        int col = ot * 16 + col0;
        float bv = bias[col];
        #pragma unroll
        for (int i = 0; i < 4; ++i) {
            int r = rbase + i;
            if (r < NN) out[(size_t)r * DIM + col] = fmaxf(acc[ot][i] + bv, 0.f);
        }
    }
}

// ===========================================================================

extern "C" void kernel_launch(void* const* d_in, const int* in_sizes, int n_in,
                              void* d_out, int out_size, void* d_ws, size_t ws_size,
                              hipStream_t stream) {
    const float* X    = (const float*)d_in[0];
    const int*   src  = (const int*)  d_in[1];
    const int*   dst  = (const int*)  d_in[2];
    const float* Ws   = (const float*)d_in[3];
    const float* Wn   = (const float*)d_in[4];
    const float* bias = (const float*)d_in[5];
    float* out = (float*)d_out;

    // tier-0 ws layout: bucketFill[256] ints | edges[196*6144] u32 |
    //   Xb (NN*DIM shorts) | aggb (NN*DIM shorts) | Wb (32768 shorts) ~= 30.5MB
    const size_t REQ0 = (size_t)256 * 4 + (size_t)NBUCK * CAP * 4
                      + (size_t)NN * DIM * 2 * 2 + (size_t)32768 * 2;
    // tier-2 (round-2 style): ~16.4 MB
    const size_t REQ2 = (size_t)(50048 + 50056 + 64 + 800000) * 4
                      + (size_t)NN * DIM * 2;

    if (ws_size >= REQ0) {
        int*      bf    = (int*)d_ws;
        unsigned* edges = (unsigned*)(bf + 256);
        short*    Xb    = (short*)(edges + (size_t)NBUCK * CAP);
        short*    aggb  = Xb + (size_t)NN * DIM;
        short*    Wb    = aggb + (size_t)NN * DIM;

        zero_k<<<1, 256, 0, stream>>>(bf);
        part1<<<3125 + PBLK + 2, 256, 0, stream>>>(X, src, dst, Ws, Wn, Xb, Wb, bf, edges);
        pull2<<<NBUCK * 4, 512, 0, stream>>>(Xb, bf, edges, aggb);
        gemm_bb<<<(NN + 127) / 128, 512, 0, stream>>>(Xb, aggb, Wb, bias, out);
    } else if (ws_size >= REQ2) {
        int* cnt      = (int*)d_ws;
        int* rowstart = cnt + 50048;
        int* bsum     = rowstart + 50056;
        int* csr      = bsum + 64;
        short* Xb     = (short*)(csr + 800000);

        hipMemsetAsync(cnt, 0, 50048 * sizeof(int), stream);
        hist_k<<<3125, 256, 0, stream>>>(dst, cnt);
        scanA<<<NBLK, 1024, 0, stream>>>(cnt, rowstart, bsum);
        scanB<<<1, 64, 0, stream>>>(bsum);
        scanC<<<NBLK, 1024, 0, stream>>>(rowstart, bsum);
        fill_atomic<<<3125, 256, 0, stream>>>(src, dst, rowstart, csr);
        cvt_k<<<3125, 256, 0, stream>>>(X, Xb);
        pull_bf16<<<12500, 256, 0, stream>>>(Xb, rowstart, csr, out);
        fused_gemm<<<(NN + 63) / 64, 256, 0, stream>>>(X, out, Ws, Wn, bias, out);
    } else {
        hipMemsetAsync(out, 0, (size_t)NN * DIM * sizeof(float), stream);
        scatter_k<<<2048, 256, 0, stream>>>(X, src, dst, out);
        fused_gemm<<<(NN + 63) / 64, 256, 0, stream>>>(X, out, Ws, Wn, bias, out);
    }
}

// Round 11
// 72.675 us; speedup vs baseline: 1.3981x; 1.0239x over previous
//
#include <hip/hip_runtime.h>
#include <hip/hip_bf16.h>

#define NN 50000
#define NE 800000
#define DIM 128
#define NBLK 49      // ceil(NN/1024) for fallback scan

// tier-0 partition geometry
#define NBUCK 196    // buckets of 256 nodes: bkt = dst>>8 (49999>>8 = 195)
#define CAP   6144   // edge capacity per bucket region (mean 4082, +32 sigma)
#define EPB   3200   // edges per partition block (250 blocks * 3200 = 800000)
#define PBLK  250
#define LCAP  2048   // per-64-node-slice LDS CSR capacity (mean 1024, +32 sigma)

typedef __attribute__((ext_vector_type(8))) short bf16x8;
typedef __attribute__((ext_vector_type(4))) float f32x4;

__device__ __forceinline__ short f2bf(float f) {
    union { float f; unsigned u; } x; x.f = f;
    unsigned r = x.u + 0x7fffu + ((x.u >> 16) & 1u);   // RNE
    return (short)(r >> 16);
}

__device__ __forceinline__ bf16x8 pack8(float4 a, float4 b) {
    bf16x8 v;
    v[0] = f2bf(a.x); v[1] = f2bf(a.y); v[2] = f2bf(a.z); v[3] = f2bf(a.w);
    v[4] = f2bf(b.x); v[5] = f2bf(b.y); v[6] = f2bf(b.z); v[7] = f2bf(b.w);
    return v;
}

__device__ __forceinline__ float bf2f(short s) {
    union { unsigned u; float f; } x; x.u = ((unsigned)(unsigned short)s) << 16;
    return x.f;
}

// Single accumulate body (round-7 lesson: one definition only).
__device__ __forceinline__ void acc8(f32x4& aA, f32x4& aB, bf16x8 x) {
    aA[0] += bf2f(x[0]); aA[1] += bf2f(x[1]); aA[2] += bf2f(x[2]); aA[3] += bf2f(x[3]);
    aB[0] += bf2f(x[4]); aB[1] += bf2f(x[5]); aB[2] += bf2f(x[6]); aB[3] += bf2f(x[7]);
}

// Graph-safe bucketFill reset.
__global__ __launch_bounds__(256) void zero_k(int* __restrict__ p) {
    p[threadIdx.x] = 0;
}

// ========================= tier-0: partition path ==========================

// blocks [0,3125): convert X -> bf16 shadow Xb.
// blocks [3125,3375): partition 3200 edges each via LDS counting sort.
// blocks 3375,3376: convert Ws/Wn -> swizzled bf16 image Wb.
__global__ __launch_bounds__(256) void part1(const float* __restrict__ X,
                                             const int* __restrict__ src,
                                             const int* __restrict__ dst,
                                             const float* __restrict__ Ws,
                                             const float* __restrict__ Wn,
                                             short* __restrict__ Xb,
                                             short* __restrict__ Wb,
                                             int* __restrict__ bucketFill,
                                             unsigned* __restrict__ edges) {
    __shared__ unsigned stage[EPB];
    __shared__ unsigned sorted_[EPB];
    __shared__ int lcnt[256];
    __shared__ int lst[256];
    __shared__ int goff[256];
    __shared__ int c2[256];

    int b = blockIdx.x;
    int t = threadIdx.x;

    if (b < 3125) {             // X convert
        int i = b * 256 + t;    // exactly 800000 items of 8 floats
        const float4* p = (const float4*)(X + (size_t)i * 8);
        *(bf16x8*)(Xb + (size_t)i * 8) = pack8(p[0], p[1]);
        return;
    }
    if (b >= 3375) {            // W convert (swizzled image, same sc as wlds)
        int w = b - 3375;       // 0: Ws, 1: Wn
        const float* Wsrc = (w == 0) ? Ws : Wn;
        for (int i = t; i < 2048; i += 256) {
            int row = i >> 4;
            int c8 = (i & 15) << 3;
            int sc = c8 ^ ((row & 15) << 3);
            const float4* p = (const float4*)(Wsrc + row * DIM + c8);
            *(bf16x8*)(Wb + (size_t)w * 16384 + row * 128 + sc) = pack8(p[0], p[1]);
        }
        return;
    }

    int pb = b - 3125;          // partition block 0..249
    int e0 = pb * EPB;
    lcnt[t] = 0; c2[t] = 0;
    __syncthreads();

    // load + count (int4)
    for (int i = t * 4; i < EPB; i += 1024) {
        int4 s4 = *(const int4*)(src + e0 + i);
        int4 d4 = *(const int4*)(dst + e0 + i);
        int ss[4] = {s4.x, s4.y, s4.z, s4.w};
        int dd[4] = {d4.x, d4.y, d4.z, d4.w};
        #pragma unroll
        for (int j = 0; j < 4; ++j) {
            unsigned bk = (unsigned)dd[j] >> 8;
            unsigned dl = (unsigned)dd[j] & 255u;
            stage[i + j] = (bk << 24) | (dl << 16) | (unsigned)ss[j];
            atomicAdd(&lcnt[bk], 1);
        }
    }
    __syncthreads();

    // inclusive scan of lcnt[0..255]
    int v = lcnt[t];
    for (int off = 1; off < 256; off <<= 1) {
        __syncthreads();
        int tmp = (t >= off) ? lcnt[t - off] : 0;
        __syncthreads();
        lcnt[t] += tmp;
    }
    __syncthreads();
    int excl = lcnt[t] - v;
    lst[t] = excl;
    if (t < NBUCK) {
        int gb = atomicAdd(&bucketFill[t], v);
        goff[t] = t * CAP + gb - excl;
    }
    __syncthreads();

    // counting sort into sorted_
    for (int i = t * 4; i < EPB; i += 1024) {
        uint4 p4 = *(const uint4*)&stage[i];
        unsigned pp[4] = {p4.x, p4.y, p4.z, p4.w};
        #pragma unroll
        for (int j = 0; j < 4; ++j) {
            int bj = pp[j] >> 24;
            int r = atomicAdd(&c2[bj], 1);
            sorted_[lst[bj] + r] = pp[j];
        }
    }
    __syncthreads();

    // stream out in coalesced per-bucket runs
    for (int i = t * 4; i < EPB; i += 1024) {
        uint4 p4 = *(const uint4*)&sorted_[i];
        unsigned pp[4] = {p4.x, p4.y, p4.z, p4.w};
        #pragma unroll
        for (int j = 0; j < 4; ++j) {
            int bj = pp[j] >> 24;
            edges[(size_t)goff[bj] + i + j] = pp[j];
        }
    }
}

// One block per (bucket, 64-node slice), XCD-grouped: all 4 slices of a
// bucket map to the SAME XCD (b = (idx>>2)*8 + bid&7) so the bucket's edge
// region is L2-shared. Bucket edges staged ONCE into LDS (est), count+fill
// both read LDS. LDS ~29KB but occupancy is wave-capped (8 waves x 4 blk/CU
// = 32) so the stage is free. Grid 800 (16 guarded-idle blocks).
__global__ __launch_bounds__(512) void pull2(const short* __restrict__ Xb,
                                             const int* __restrict__ bucketFill,
                                             const unsigned* __restrict__ edges,
                                             short* __restrict__ aggb) {
    __shared__ __align__(16) unsigned est[CAP];      // 24 KB edge stage
    __shared__ int cnt[64];
    __shared__ int c2s[64];
    __shared__ int start[65];
    __shared__ unsigned short lcsr[LCAP];            // 4 KB

    int t = threadIdx.x;
    int xcd = blockIdx.x & 7;
    int idx = blockIdx.x >> 3;
    int b  = (idx >> 2) * 8 + xcd;          // bucket (4 slices share an XCD)
    int sl = idx & 3;                       // 64-node slice
    if (b >= NBUCK) return;
    int dlo = sl * 64;
    int m = bucketFill[b];
    if (m > CAP) m = CAP;
    const unsigned* ed = edges + (size_t)b * CAP;

    if (t < 64) { cnt[t] = 0; c2s[t] = 0; }
    __syncthreads();

    // stage edges -> LDS and count owned dlocs (single global pass, uint4)
    for (int i = t * 4; i < m; i += 2048) {
        if (i + 4 <= m) {
            uint4 e4 = *(const uint4*)(ed + i);
            *(uint4*)&est[i] = e4;
            unsigned pp[4] = {e4.x, e4.y, e4.z, e4.w};
            #pragma unroll
            for (int j = 0; j < 4; ++j) {
                int o = ((pp[j] >> 16) & 255u) - dlo;
                if ((unsigned)o < 64u) atomicAdd(&cnt[o], 1);
            }
        } else {
            for (int k = i; k < m; ++k) {
                unsigned p = ed[k];
                est[k] = p;
                int o = ((p >> 16) & 255u) - dlo;
                if ((unsigned)o < 64u) atomicAdd(&cnt[o], 1);
            }
        }
    }
    __syncthreads();

    // exclusive scan of 64 counts
    int v = (t < 64) ? cnt[t] : 0;
    for (int off = 1; off < 64; off <<= 1) {
        __syncthreads();
        int tmp = (t >= off && t < 64) ? cnt[t - off] : 0;
        __syncthreads();
        if (t < 64) cnt[t] += tmp;
    }
    __syncthreads();
    if (t < 64) start[t] = cnt[t] - v;
    if (t == 63) start[64] = cnt[63];
    __syncthreads();

    // fill slice CSR from LDS stage
    for (int i = t; i < m; i += 512) {
        unsigned p = est[i];
        int o = ((p >> 16) & 255u) - dlo;
        if ((unsigned)o < 64u) {
            int r = atomicAdd(&c2s[o], 1);
            int idx2 = start[o] + r;
            if (idx2 < LCAP) lcsr[idx2] = (unsigned short)(p & 0xffffu);
        }
    }
    __syncthreads();

    // pull: 8 waves, 8 nodes each; 16 lanes x 16B per row, 4 row-slots/load
    int lane = t & 63, wv = t >> 6;
    int g = lane >> 4, fl = lane & 15;
    const short* xbase = Xb + fl * 8;
    for (int n = wv; n < 64; n += 8) {
        int u = (b << 8) + dlo + n;
        if (u >= NN) continue;
        int beg = start[n], end = start[n + 1];
        if (beg > LCAP) beg = LCAP;
        if (end > LCAP) end = LCAP;
        f32x4 aA = {0.f, 0.f, 0.f, 0.f}, aB = {0.f, 0.f, 0.f, 0.f};
        int e = beg;
        for (; e + 16 <= end; e += 16) {          // 4 row-loads in flight
            int v0 = lcsr[e + g];
            int v1 = lcsr[e + 4 + g];
            int v2 = lcsr[e + 8 + g];
            int v3 = lcsr[e + 12 + g];
            bf16x8 x0 = *(const bf16x8*)(xbase + (size_t)v0 * DIM);
            bf16x8 x1 = *(const bf16x8*)(xbase + (size_t)v1 * DIM);
            bf16x8 x2 = *(const bf16x8*)(xbase + (size_t)v2 * DIM);
            bf16x8 x3 = *(const bf16x8*)(xbase + (size_t)v3 * DIM);
            acc8(aA, aB, x0); acc8(aA, aB, x1);
            acc8(aA, aB, x2); acc8(aA, aB, x3);
        }
        for (; e + 8 <= end; e += 8) {
            int v0 = lcsr[e + g];
            int v1 = lcsr[e + 4 + g];
            bf16x8 x0 = *(const bf16x8*)(xbase + (size_t)v0 * DIM);
            bf16x8 x1 = *(const bf16x8*)(xbase + (size_t)v1 * DIM);
            acc8(aA, aB, x0); acc8(aA, aB, x1);
        }
        for (; e < end; e += 4) {
            int idx2 = e + g;
            int vv = lcsr[idx2 < end ? idx2 : beg];
            bf16x8 x = *(const bf16x8*)(xbase + (size_t)vv * DIM);
            if (idx2 < end) acc8(aA, aB, x);
        }
        #pragma unroll
        for (int i = 0; i < 4; ++i) {
            aA[i] += __shfl_xor(aA[i], 16); aA[i] += __shfl_xor(aA[i], 32);
            aB[i] += __shfl_xor(aB[i], 16); aB[i] += __shfl_xor(aB[i], 32);
        }
        if (g == 0) {
            bf16x8 r;
            r[0] = f2bf(aA[0]); r[1] = f2bf(aA[1]); r[2] = f2bf(aA[2]); r[3] = f2bf(aA[3]);
            r[4] = f2bf(aB[0]); r[5] = f2bf(aB[1]); r[6] = f2bf(aB[2]); r[7] = f2bf(aB[3]);
            *(bf16x8*)(aggb + (size_t)u * DIM + fl * 8) = r;
        }
    }
}

// out = ReLU(Xb@Ws^T + aggb@Wn^T + bias). 128-row blocks, 8 waves (512 thr);
// W staged by flat copy of the preconverted swizzled Wb image.
__global__ __launch_bounds__(512) void gemm_bb(const short* __restrict__ Xb,
                                               const short* __restrict__ aggb,
                                               const short* __restrict__ Wb,
                                               const float* __restrict__ bias,
                                               float* __restrict__ out) {
    __shared__ __align__(16) short wlds[2][128][128];
    for (int i = threadIdx.x; i < 4096; i += 512)
        *(bf16x8*)((short*)wlds + (size_t)i * 8) = *(const bf16x8*)(Wb + (size_t)i * 8);
    __syncthreads();

    int lane = threadIdx.x & 63;
    int wv = threadIdx.x >> 6;                 // 0..7
    int n0 = blockIdx.x * 128 + wv * 16;
    int arow = n0 + (lane & 15);
    int rowc = arow < NN ? arow : (NN - 1);
    const short* xr = Xb   + (size_t)rowc * DIM + (lane >> 4) * 8;
    const short* ar = aggb + (size_t)rowc * DIM + (lane >> 4) * 8;

    f32x4 acc[8] = {};
    #pragma unroll
    for (int ks = 0; ks < 4; ++ks) {
        int k0 = ks * 32;
        bf16x8 afx = *(const bf16x8*)(xr + k0);
        bf16x8 afg = *(const bf16x8*)(ar + k0);
        int bcol = k0 + (lane >> 4) * 8;
        #pragma unroll
        for (int ot = 0; ot < 8; ++ot) {
            int brow = ot * 16 + (lane & 15);
            int sc = bcol ^ ((brow & 15) << 3);
            bf16x8 bs = *(const bf16x8*)&wlds[0][brow][sc];
            bf16x8 bn = *(const bf16x8*)&wlds[1][brow][sc];
            acc[ot] = __builtin_amdgcn_mfma_f32_16x16x32_bf16(afx, bs, acc[ot], 0, 0, 0);
            acc[ot] = __builtin_amdgcn_mfma_f32_16x16x32_bf16(afg, bn, acc[ot], 0, 0, 0);
        }
    }

    int col0 = lane & 15;
    int rbase = n0 + (lane >> 4) * 4;
    #pragma unroll
    for (int ot = 0; ot < 8; ++ot) {
        int col = ot * 16 + col0;
        float bv = bias[col];
        #pragma unroll
        for (int i = 0; i < 4; ++i) {
            int r = rbase + i;
            if (r < NN) out[(size_t)r * DIM + col] = fmaxf(acc[ot][i] + bv, 0.f);
        }
    }
}

// ===================== tier-2/3 fallback kernels ===========================

__global__ __launch_bounds__(256) void hist_k(const int* __restrict__ dst,
                                              int* __restrict__ cnt) {
    int e = blockIdx.x * 256 + threadIdx.x;
    if (e < NE) atomicAdd(&cnt[dst[e]], 1);
}

__global__ __launch_bounds__(1024) void scanA(const int* __restrict__ cnt,
                                              int* __restrict__ rowstart,
                                              int* __restrict__ bsum) {
    __shared__ int s[1024];
    int i = blockIdx.x * 1024 + threadIdx.x;
    int v = (i < NN) ? cnt[i] : 0;
    s[threadIdx.x] = v;
    for (int off = 1; off < 1024; off <<= 1) {
        __syncthreads();
        int t = (threadIdx.x >= off) ? s[threadIdx.x - off] : 0;
        __syncthreads();
        s[threadIdx.x] += t;
    }
    __syncthreads();
    if (i < NN) rowstart[i] = s[threadIdx.x] - v;
    if (threadIdx.x == 1023) bsum[blockIdx.x] = s[1023];
}

__global__ __launch_bounds__(64) void scanB(int* __restrict__ bsum) {
    int l = threadIdx.x;
    int orig = (l < NBLK) ? bsum[l] : 0;
    int v = orig;
    for (int off = 1; off < 64; off <<= 1) {
        int t = __shfl_up(v, off);
        if (l >= off) v += t;
    }
    if (l < NBLK) bsum[l] = v - orig;
}

__global__ __launch_bounds__(1024) void scanC(int* __restrict__ rowstart,
                                              const int* __restrict__ bsum) {
    int i = blockIdx.x * 1024 + threadIdx.x;
    if (i < NN) rowstart[i] += bsum[blockIdx.x];
    if (i == 0) rowstart[NN] = NE;
}

__global__ __launch_bounds__(256) void fill_atomic(const int* __restrict__ src,
                                                   const int* __restrict__ dst,
                                                   int* __restrict__ rowstart,
                                                   int* __restrict__ csr) {
    int e = blockIdx.x * 256 + threadIdx.x;
    if (e < NE) {
        int p = atomicAdd(&rowstart[dst[e]], 1);
        csr[p] = src[e];
    }
}

__global__ __launch_bounds__(256) void cvt_k(const float* __restrict__ X,
                                             short* __restrict__ Xb) {
    int i = blockIdx.x * 256 + threadIdx.x;
    if (i < NN * DIM / 8) {
        const float4* p = (const float4*)(X + (size_t)i * 8);
        *(bf16x8*)(Xb + (size_t)i * 8) = pack8(p[0], p[1]);
    }
}

__global__ __launch_bounds__(256) void pull_bf16(const short* __restrict__ Xb,
                                                 const int* __restrict__ rowend,
                                                 const int* __restrict__ csr,
                                                 float* __restrict__ agg) {
    int lane = threadIdx.x & 63;
    int u = (blockIdx.x * 256 + threadIdx.x) >> 6;
    if (u >= NN) return;
    int beg = (u == 0) ? 0 : rowend[u - 1];
    int end = rowend[u];
    float2 a0 = {0.f, 0.f}, a1 = {0.f, 0.f};
    int e = beg;
    for (; e + 1 < end; e += 2) {
        int v0 = csr[e], v1 = csr[e + 1];
        ushort2 x0 = *(const ushort2*)(Xb + (size_t)v0 * DIM + lane * 2);
        ushort2 x1 = *(const ushort2*)(Xb + (size_t)v1 * DIM + lane * 2);
        a0.x += bf2f(x0.x); a0.y += bf2f(x0.y);
        a1.x += bf2f(x1.x); a1.y += bf2f(x1.y);
    }
    if (e < end) {
        int v0 = csr[e];
        ushort2 x0 = *(const ushort2*)(Xb + (size_t)v0 * DIM + lane * 2);
        a0.x += bf2f(x0.x); a0.y += bf2f(x0.y);
    }
    float2 r = {a0.x + a1.x, a0.y + a1.y};
    *(float2*)(agg + (size_t)u * DIM + lane * 2) = r;
}

__global__ __launch_bounds__(256) void scatter_k(const float* __restrict__ X,
                                                 const int* __restrict__ src,
                                                 const int* __restrict__ dst,
                                                 float* __restrict__ agg) {
    int lane = threadIdx.x & 63;
    int gw = (blockIdx.x * 256 + threadIdx.x) >> 6;
    int nw = (gridDim.x * 256) >> 6;
    for (int e = gw; e < NE; e += nw) {
        int s = src[e];
        int d = dst[e];
        float2 v = *(const float2*)(X + (size_t)s * DIM + lane * 2);
        float* a = agg + (size_t)d * DIM + lane * 2;
        unsafeAtomicAdd(a, v.x);
        unsafeAtomicAdd(a + 1, v.y);
    }
}

__global__ __launch_bounds__(256) void fused_gemm(
        const float* __restrict__ X,
        const float* __restrict__ agg,
        const float* __restrict__ Ws,
        const float* __restrict__ Wn,
        const float* __restrict__ bias,
        float* __restrict__ out) {
    __shared__ __align__(16) short wlds[2][128][128];
    for (int i = threadIdx.x; i < 128 * 16; i += 256) {
        int row = i >> 4;
        int c8 = (i & 15) << 3;
        int sc = c8 ^ ((row & 15) << 3);
        const float4* ps = (const float4*)(Ws + row * DIM + c8);
        *(bf16x8*)&wlds[0][row][sc] = pack8(ps[0], ps[1]);
        const float4* pn = (const float4*)(Wn + row * DIM + c8);
        *(bf16x8*)&wlds[1][row][sc] = pack8(pn[0], pn[1]);
    }
    __syncthreads();

    int lane = threadIdx.x & 63;
    int wv = threadIdx.x >> 6;
    int n0 = blockIdx.x * 64 + wv * 16;
    int arow = n0 + (lane & 15);
    int rowc = arow < NN ? arow : (NN - 1);
    const float* xr = X + (size_t)rowc * DIM + (lane >> 4) * 8;
    const float* ar = agg + (size_t)rowc * DIM + (lane >> 4) * 8;

    f32x4 acc[8] = {};
    #pragma unroll
    for (int ks = 0; ks < 4; ++ks) {
        int k0 = ks * 32;
        float4 xa = *(const float4*)(xr + k0);
        float4 xb = *(const float4*)(xr + k0 + 4);
        bf16x8 afx = pack8(xa, xb);
        float4 ga = *(const float4*)(ar + k0);
        float4 gb = *(const float4*)(ar + k0 + 4);
        bf16x8 afg = pack8(ga, gb);
        int bcol = k0 + (lane >> 4) * 8;
        #pragma unroll
        for (int ot = 0; ot < 8; ++ot) {
            int brow = ot * 16 + (lane & 15);
            int sc = bcol ^ ((brow & 15) << 3);
            bf16x8 bs = *(const bf16x8*)&wlds[0][brow][sc];
            bf16x8 bn = *(const bf16x8*)&wlds[1][brow][sc];
            acc[ot] = __builtin_amdgcn_mfma_f32_16x16x32_bf16(afx, bs, acc[ot], 0, 0, 0);
            acc[ot] = __builtin_amdgcn_mfma_f32_16x16x32_bf16(afg, bn, acc[ot], 0, 0, 0);
        }
    }

    int col0 = lane & 15;
    int rbase = n0 + (lane >> 4) * 4;
    #pragma unroll
    for (int ot = 0; ot < 8; ++ot) {
        int col = ot * 16 + col0;
        float bv = bias[col];
        #pragma unroll
        for (int i = 0; i < 4; ++i) {
            int r = rbase + i;
            if (r < NN) out[(size_t)r * DIM + col] = fmaxf(acc[ot][i] + bv, 0.f);
        }
    }
}

// ===========================================================================

extern "C" void kernel_launch(void* const* d_in, const int* in_sizes, int n_in,
                              void* d_out, int out_size, void* d_ws, size_t ws_size,
                              hipStream_t stream) {
    const float* X    = (const float*)d_in[0];
    const int*   src  = (const int*)  d_in[1];
    const int*   dst  = (const int*)  d_in[2];
    const float* Ws   = (const float*)d_in[3];
    const float* Wn   = (const float*)d_in[4];
    const float* bias = (const float*)d_in[5];
    float* out = (float*)d_out;

    // tier-0 ws layout: bucketFill[256] ints | edges[196*6144] u32 |
    //   Xb (NN*DIM shorts) | aggb (NN*DIM shorts) | Wb (32768 shorts) ~= 30.5MB
    const size_t REQ0 = (size_t)256 * 4 + (size_t)NBUCK * CAP * 4
                      + (size_t)NN * DIM * 2 * 2 + (size_t)32768 * 2;
    // tier-2 (round-2 style): ~16.4 MB
    const size_t REQ2 = (size_t)(50048 + 50056 + 64 + 800000) * 4
                      + (size_t)NN * DIM * 2;

    if (ws_size >= REQ0) {
        int*      bf    = (int*)d_ws;
        unsigned* edges = (unsigned*)(bf + 256);
        short*    Xb    = (short*)(edges + (size_t)NBUCK * CAP);
        short*    aggb  = Xb + (size_t)NN * DIM;
        short*    Wb    = aggb + (size_t)NN * DIM;

        zero_k<<<1, 256, 0, stream>>>(bf);
        part1<<<3125 + PBLK + 2, 256, 0, stream>>>(X, src, dst, Ws, Wn, Xb, Wb, bf, edges);
        pull2<<<800, 512, 0, stream>>>(Xb, bf, edges, aggb);
        gemm_bb<<<(NN + 127) / 128, 512, 0, stream>>>(Xb, aggb, Wb, bias, out);
    } else if (ws_size >= REQ2) {
        int* cnt      = (int*)d_ws;
        int* rowstart = cnt + 50048;
        int* bsum     = rowstart + 50056;
        int* csr      = bsum + 64;
        short* Xb     = (short*)(csr + 800000);

        hipMemsetAsync(cnt, 0, 50048 * sizeof(int), stream);
        hist_k<<<3125, 256, 0, stream>>>(dst, cnt);
        scanA<<<NBLK, 1024, 0, stream>>>(cnt, rowstart, bsum);
        scanB<<<1, 64, 0, stream>>>(bsum);
        scanC<<<NBLK, 1024, 0, stream>>>(rowstart, bsum);
        fill_atomic<<<3125, 256, 0, stream>>>(src, dst, rowstart, csr);
        cvt_k<<<3125, 256, 0, stream>>>(X, Xb);
        pull_bf16<<<12500, 256, 0, stream>>>(Xb, rowstart, csr, out);
        fused_gemm<<<(NN + 63) / 64, 256, 0, stream>>>(X, out, Ws, Wn, bias, out);
    } else {
        hipMemsetAsync(out, 0, (size_t)NN * DIM * sizeof(float), stream);
        scatter_k<<<2048, 256, 0, stream>>>(X, src, dst, out);
        fused_gemm<<<(NN + 63) / 64, 256, 0, stream>>>(X, out, Ws, Wn, bias, out);
    }
}